// Round 14
// baseline (97.242 us; speedup 1.0000x reference)
//
#include <hip/hip_runtime.h>
#include <math.h>

// Problem constants (from reference)
#define P_TOTAL 10000
#define G_TOTAL 6400
#define C_CLS   18
#define CS_SH   3                   // cell = 8 voxels = 4 m
#define NCX     25
#define NCELL   (NCX * NCX)         // 625
#define MAXE    256                 // box entries per cell (mean ~54)
#define PCAP    64                  // points per cell (mean 16, obs max <= 64: R11 passed)
#define NBLK    256                 // one block per CU -> guaranteed co-resident
#define NTHR    256                 // 4 waves per block
#define HB      16                  // hits per MLP batch in gather

// Workspace layout (bytes). Memset region = [0, 8192): bar + counts + pcnt.
#define OFF_BAR    0
#define OFF_CNT    64
#define OFF_PCNT   4096
#define OFF_PLIST  8192
#define OFF_ENT    (8192 + NCELL * PCAP * 4)   // 168192, 16B aligned

__global__ void __launch_bounds__(NTHR, 4)
la_bar(const float* __restrict__ pts,
       const float* __restrict__ means3D,
       const float* __restrict__ opacities,
       const float* __restrict__ semantics,
       const float* __restrict__ scales,
       const float* __restrict__ cov3D,
       char* __restrict__ ws,
       float* __restrict__ out) {
    int*  bar     = (int*)(ws + OFF_BAR);
    int*  counts  = (int*)(ws + OFF_CNT);
    int*  pcnt    = (int*)(ws + OFF_PCNT);
    int*  plist   = (int*)(ws + OFF_PLIST);
    int4* entries = (int4*)(ws + OFF_ENT);

    const int t = threadIdx.x;
    const int gtid = blockIdx.x * NTHR + t;      // 0..65535

    // ---- phase 1a: bin points, one per thread (each point touched ONCE) ----
    if (gtid < P_TOTAL) {
        float px = pts[gtid * 3 + 0];
        float py = pts[gtid * 3 + 1];
        int cx = ((int)((px + 50.0f) * 2.0f)) >> CS_SH;
        int cy = ((int)((py + 50.0f) * 2.0f)) >> CS_SH;
        int cell = cy * NCX + cx;
        int s = atomicAdd(&pcnt[cell], 1);
        if (s < PCAP) plist[cell * PCAP + s] = gtid;
    }

    // ---- phase 1b: bin gaussians, one per thread (each box computed ONCE) ----
    if (gtid < G_TOTAL) {
        int g = gtid;
        float mx = means3D[g * 3 + 0];
        float my = means3D[g * 3 + 1];
        float mz = means3D[g * 3 + 2];
        float sx = scales[g * 3 + 0];
        float sy = scales[g * 3 + 1];
        float sz = scales[g * 3 + 2];
        // (mu - PC_MIN)/0.5 == (mu - PC_MIN)*2 exactly
        int mix = (int)((mx + 50.0f) * 2.0f);
        int miy = (int)((my + 50.0f) * 2.0f);
        int miz = (int)((mz + 5.0f) * 2.0f);
        // radii = ceil(max(s)*3.0/0.5): *3.0 rounds, *2 exact
        int r = (int)ceilf((fmaxf(fmaxf(sx, sy), sz) * 3.0f) * 2.0f);
        int w = 2 * r;
        int minx = mix - r, miny = miy - r, minz = miz - r;
        int cx0 = max(minx, 0) >> CS_SH;
        int cx1 = min(minx + w, 199) >> CS_SH;
        int cy0 = max(miny, 0) >> CS_SH;
        int cy1 = min(miny + w, 199) >> CS_SH;
        int4 e = make_int4(minx, miny, minz, (w << 16) | g);
        for (int cy = cy0; cy <= cy1; ++cy) {
            for (int cx = cx0; cx <= cx1; ++cx) {
                int cell = cy * NCX + cx;
                int s = atomicAdd(&counts[cell], 1);
                if (s < MAXE) entries[(size_t)cell * MAXE + s] = e;
            }
        }
    }

    // ---- resident-grid software barrier (256 blocks, guaranteed co-resident) ----
    __threadfence();                 // make my bins visible device-wide
    __syncthreads();
    if (t == 0) {
        atomicAdd(&bar[0], 1);
        while (atomicAdd(&bar[0], 0) < NBLK)
            __builtin_amdgcn_s_sleep(8);
    }
    __syncthreads();                 // releases whole block after thread 0 observes
    __threadfence();

    // ---- phase 2: gather; block b handles cells b, b+256, b+512 ----
    __shared__ int4 sbox[MAXE];      // 4 KB
    __shared__ int  spl[PCAP];
    const int wv = t >> 6, lane = t & 63;

    for (int cell = blockIdx.x; cell < NCELL; cell += NBLK) {
        int nb = min(counts[cell], MAXE);
        int np = min(pcnt[cell], PCAP);
        __syncthreads();             // protect sbox/spl reuse across cell iterations
        for (int i = t; i < nb; i += NTHR) sbox[i] = entries[(size_t)cell * MAXE + i];
        for (int i = t; i < np; i += NTHR) spl[i] = plist[cell * PCAP + i];
        __syncthreads();

        for (int idx = wv; idx < np; idx += NTHR / 64) {
            int pt = spl[idx];
            float px = pts[pt * 3 + 0];
            float py = pts[pt * 3 + 1];
            float pz = pts[pt * 3 + 2];
            int pix = (int)((px + 50.0f) * 2.0f);
            int piy = (int)((py + 50.0f) * 2.0f);
            int piz = (int)((pz + 5.0f) * 2.0f);

            float acc = 0.0f;        // lane c (<18) accumulates class c
            for (int base = 0; base < nb; base += 64) {
                int i = base + lane;
                float wgt = 0.0f;
                int gid = 0;
                if (i < nb) {
                    int4 b = sbox[i];
                    unsigned w  = ((unsigned)b.w) >> 16;
                    unsigned ux = (unsigned)(pix - b.x);
                    unsigned uy = (unsigned)(piy - b.y);
                    unsigned uz = (unsigned)(piz - b.z);
                    if (ux <= w && uy <= w && uz <= w) {
                        gid = b.w & 0xffff;
                        float mx = means3D[gid * 3 + 0];
                        float my = means3D[gid * 3 + 1];
                        float mz = means3D[gid * 3 + 2];
                        const float* cv = cov3D + (size_t)gid * 9;
                        float dx = px - mx, dy = py - my, dz = pz - mz;
                        float pw = -0.5f * (cv[0] * dx * dx + cv[4] * dy * dy + cv[8] * dz * dz)
                                   - cv[1] * dx * dy - cv[5] * dy * dz - cv[2] * dx * dz;
                        wgt = __expf(pw) * opacities[gid];
                    }
                }
                // batched hit processing: collect via shuffles, then issue all
                // semantics loads independently (breaks dependent-load chain)
                unsigned long long m = __ballot(wgt != 0.0f);
                while (m) {
                    float wh[HB];
                    int   gh[HB];
#pragma unroll
                    for (int k = 0; k < HB; ++k) {
                        bool has = (m != 0);
                        int h = (int)__builtin_ctzll(m | 0x8000000000000000ULL);
                        float w_ = __shfl(wgt, h, 64);   // uniform index -> readlane
                        int   g_ = __shfl(gid, h, 64);
                        wh[k] = has ? w_ : 0.0f;         // wgt=0 -> fma identity
                        gh[k] = has ? g_ : 0;
                        m &= m - 1;
                    }
                    if (lane < C_CLS) {
#pragma unroll
                        for (int k = 0; k < HB; ++k)
                            acc = fmaf(wh[k], semantics[(size_t)gh[k] * C_CLS + lane], acc);
                    }
                }
            }

            if (lane < C_CLS)
                out[(size_t)pt * C_CLS + lane] = acc;    // coalesced 72B per point
        }
    }
}

extern "C" void kernel_launch(void* const* d_in, const int* in_sizes, int n_in,
                              void* d_out, int out_size, void* d_ws, size_t ws_size,
                              hipStream_t stream) {
    const float* pts      = (const float*)d_in[0];
    const float* means3D  = (const float*)d_in[1];
    const float* opac     = (const float*)d_in[2];
    const float* sem      = (const float*)d_in[3];
    const float* scales   = (const float*)d_in[4];
    const float* cov3D    = (const float*)d_in[5];
    float* out = (float*)d_out;
    char* ws = (char*)d_ws;

    // zero barrier + counters (8 KB) each call; entries/plist gated by counts
    hipMemsetAsync(ws, 0, 8192, stream);
    la_bar<<<NBLK, NTHR, 0, stream>>>(pts, means3D, opac, sem, scales, cov3D, ws, out);
}

// Round 15
// 28.569 us; speedup vs baseline: 3.4037x; 3.4037x over previous
//
#include <hip/hip_runtime.h>
#include <math.h>

// Problem constants (from reference)
#define P_TOTAL 10000
#define G_TOTAL 6400
#define C_CLS   18
#define CS_SH   3                   // cell = 8 voxels = 4 m
#define NCX     25
#define NCELL   (NCX * NCX)         // 625
#define BCAP    256                 // boxes per cell (mean ~54, max ~150)
#define PCAP    96                  // points per cell (mean 16, max ~40)
#define NTHR    512                 // 8 waves per block
#define HB      16                  // hits processed per batch (MLP width)
#define PT_THR  320                 // threads 0..319 sweep points (5 waves)
                                    // threads 320..511 sweep gaussians (3 waves)

// Single fused kernel: block = cell. CONCURRENT sweeps (point-sweep waves 0-4
// run in parallel with gaussian-sweep waves 5-7), then wave-per-point gather
// with batched hit processing.
__global__ void __launch_bounds__(NTHR)
la_cell5(const float* __restrict__ pts,
         const float* __restrict__ means3D,
         const float* __restrict__ opacities,
         const float* __restrict__ semantics,
         const float* __restrict__ scales,
         const float* __restrict__ cov3D,
         float* __restrict__ out) {
    __shared__ int4 sbox[BCAP];     // 4 KB
    __shared__ int  splist[PCAP];
    __shared__ int  snb, snp;

    const int t = threadIdx.x;
    const int cell = blockIdx.x;
    const int ccx = cell % NCX;
    const int ccy = cell / NCX;

    if (t == 0) { snb = 0; snp = 0; }
    __syncthreads();

    if (t < PT_THR) {
        // ---- point sweep: 4 points per iteration, waves 0-4 ----
        const float4* p4 = (const float4*)pts;
        for (int j = t; j < P_TOTAL / 4; j += PT_THR) {
            float4 a = p4[j * 3 + 0];
            float4 b = p4[j * 3 + 1];
            float4 c = p4[j * 3 + 2];
            float pxs[4] = {a.x, a.w, b.z, c.y};
            float pys[4] = {a.y, b.x, b.w, c.z};
#pragma unroll
            for (int q = 0; q < 4; ++q) {
                int cx = ((int)((pxs[q] + 50.0f) * 2.0f)) >> CS_SH;
                int cy = ((int)((pys[q] + 50.0f) * 2.0f)) >> CS_SH;
                if (cx == ccx && cy == ccy) {
                    int s = atomicAdd(&snp, 1);
                    if (s < PCAP) splist[s] = j * 4 + q;
                }
            }
        }
    } else {
        // ---- gaussian sweep: 4 gaussians per iteration, waves 5-7 ----
        const int tg = t - PT_THR;                  // 0..191
        const int GT = NTHR - PT_THR;               // 192
        const float4* m4 = (const float4*)means3D;
        const float4* s4 = (const float4*)scales;
        for (int j = tg; j < G_TOTAL / 4; j += GT) {
            float4 ma = m4[j * 3 + 0], mb = m4[j * 3 + 1], mc = m4[j * 3 + 2];
            float4 sa = s4[j * 3 + 0], sb = s4[j * 3 + 1], sc = s4[j * 3 + 2];
            float mxs[4] = {ma.x, ma.w, mb.z, mc.y};
            float mys[4] = {ma.y, mb.x, mb.w, mc.z};
            float mzs[4] = {ma.z, mb.y, mc.x, mc.w};
            float sxs[4] = {sa.x, sa.w, sb.z, sc.y};
            float sys[4] = {sa.y, sb.x, sb.w, sc.z};
            float szs[4] = {sa.z, sb.y, sc.x, sc.w};
#pragma unroll
            for (int q = 0; q < 4; ++q) {
                // (mu - PC_MIN)/0.5 == (mu - PC_MIN)*2 exactly
                int mix = (int)((mxs[q] + 50.0f) * 2.0f);
                int miy = (int)((mys[q] + 50.0f) * 2.0f);
                int miz = (int)((mzs[q] + 5.0f) * 2.0f);
                // radii = ceil(max(s)*3.0/0.5): *3.0 rounds, *2 exact
                int r = (int)ceilf((fmaxf(fmaxf(sxs[q], sys[q]), szs[q]) * 3.0f) * 2.0f);
                int w = 2 * r;
                int minx = mix - r, miny = miy - r, minz = miz - r;
                int cx0 = max(minx, 0) >> CS_SH;
                int cx1 = min(minx + w, 199) >> CS_SH;
                int cy0 = max(miny, 0) >> CS_SH;
                int cy1 = min(miny + w, 199) >> CS_SH;
                if (ccx >= cx0 && ccx <= cx1 && ccy >= cy0 && ccy <= cy1) {
                    int s = atomicAdd(&snb, 1);
                    if (s < BCAP)
                        sbox[s] = make_int4(minx, miny, minz, (w << 16) | (j * 4 + q));
                }
            }
        }
    }
    __syncthreads();

    const int np = min(snp, PCAP);
    const int nb = min(snb, BCAP);
    const int wv = t >> 6, lane = t & 63;      // 8 waves per block

    // phase 3: wave-per-point gather; lanes 0..17 accumulate classes.
    for (int idx = wv; idx < np; idx += NTHR / 64) {
        int pt = splist[idx];
        float px = pts[pt * 3 + 0];
        float py = pts[pt * 3 + 1];
        float pz = pts[pt * 3 + 2];
        int pix = (int)((px + 50.0f) * 2.0f);
        int piy = (int)((py + 50.0f) * 2.0f);
        int piz = (int)((pz + 5.0f) * 2.0f);

        float acc = 0.0f;
        for (int base = 0; base < nb; base += 64) {
            int i = base + lane;
            float wgt = 0.0f;
            int gid = 0;
            if (i < nb) {
                int4 b = sbox[i];
                unsigned w  = ((unsigned)b.w) >> 16;
                unsigned ux = (unsigned)(pix - b.x);
                unsigned uy = (unsigned)(piy - b.y);
                unsigned uz = (unsigned)(piz - b.z);
                if (ux <= w && uy <= w && uz <= w) {
                    gid = b.w & 0xffff;
                    float mx = means3D[gid * 3 + 0];
                    float my = means3D[gid * 3 + 1];
                    float mz = means3D[gid * 3 + 2];
                    const float* cv = cov3D + (size_t)gid * 9;
                    float dx = px - mx, dy = py - my, dz = pz - mz;
                    float pw = -0.5f * (cv[0] * dx * dx + cv[4] * dy * dy + cv[8] * dz * dz)
                               - cv[1] * dx * dy - cv[5] * dy * dz - cv[2] * dx * dz;
                    wgt = __expf(pw) * opacities[gid];
                }
            }

            // batched hit processing: collect up to HB hits with shuffles only,
            // then issue all HB semantics loads independently (MLP ~13).
            unsigned long long m = __ballot(wgt != 0.0f);
            while (m) {
                float wh[HB];
                int   gh[HB];
#pragma unroll
                for (int k = 0; k < HB; ++k) {
                    bool has = (m != 0);
                    int h = (int)__builtin_ctzll(m | 0x8000000000000000ULL);
                    float w_ = __shfl(wgt, h, 64);   // uniform index -> readlane
                    int   g_ = __shfl(gid, h, 64);
                    wh[k] = has ? w_ : 0.0f;         // wgt=0 -> fma is identity
                    gh[k] = has ? g_ : 0;            // dummy load hits sem[0..17]
                    m &= m - 1;
                }
                if (lane < C_CLS) {
#pragma unroll
                    for (int k = 0; k < HB; ++k)
                        acc = fmaf(wh[k], semantics[(size_t)gh[k] * C_CLS + lane], acc);
                }
            }
        }

        if (lane < C_CLS)
            out[(size_t)pt * C_CLS + lane] = acc;   // coalesced 72B per point
    }
}

extern "C" void kernel_launch(void* const* d_in, const int* in_sizes, int n_in,
                              void* d_out, int out_size, void* d_ws, size_t ws_size,
                              hipStream_t stream) {
    const float* pts      = (const float*)d_in[0];
    const float* means3D  = (const float*)d_in[1];
    const float* opac     = (const float*)d_in[2];
    const float* sem      = (const float*)d_in[3];
    const float* scales   = (const float*)d_in[4];
    const float* cov3D    = (const float*)d_in[5];
    float* out = (float*)d_out;

    la_cell5<<<NCELL, NTHR, 0, stream>>>(pts, means3D, opac, sem, scales, cov3D, out);
}